// Round 18
// baseline (373.899 us; speedup 1.0000x reference)
//
#include <hip/hip_runtime.h>
#include <stdint.h>

#define Bb 4
#define Tt 2048
#define Cc 1024
#define Hh 16
#define HSs 64

typedef __attribute__((ext_vector_type(8))) __bf16 bf16x8;
typedef __attribute__((ext_vector_type(4))) float f32x4;

// round-half-up bf16 cast: 2 VALU ops (vs 4 for RNE). Ties differ from RNE only.
__device__ __forceinline__ ushort f2bf(float f){
  union { float f; uint u; } c; c.f = f;
  return (ushort)((c.u + 0x8000u) >> 16);
}
__device__ __forceinline__ float bf2f(ushort u){
  union { uint u; float f; } c; c.u = ((uint)u) << 16; return c.f;
}

// async global->LDS, 16B per lane. LDS dest wave-uniform base; HW adds lane*16.
__device__ __forceinline__ void gload16(const void* g, void* l){
  __builtin_amdgcn_global_load_lds(
      (__attribute__((address_space(1))) void*)(g),
      (__attribute__((address_space(3))) void*)(l), 16, 0, 0);
}

// ---------------- merged fp32 -> bf16 weight cast ----------------
__global__ __launch_bounds__(256) void cast_all_kernel(
    const float* __restrict__ wq, const float* __restrict__ wk,
    const float* __restrict__ wv, const float* __restrict__ w1,
    const float* __restrict__ w2, ushort* __restrict__ out){
  int i = (blockIdx.x * 256 + threadIdx.x) * 4;
  const float* src; int off;
  if      (i <  1048576){ src = wq; off = i; }
  else if (i <  2097152){ src = wk; off = i - 1048576; }
  else if (i <  3145728){ src = wv; off = i - 2097152; }
  else if (i <  7340032){ src = w1; off = i - 3145728; }
  else                  { src = w2; off = i - 7340032; }
  float4 v = *(const float4*)(src + off);
  ushort4 o; o.x = f2bf(v.x); o.y = f2bf(v.y); o.z = f2bf(v.z); o.w = f2bf(v.w);
  *(ushort4*)(out + i) = o;
}

// ---------------- FFN2 finish: out += p0 + p1 + bias ----------------
__global__ __launch_bounds__(256) void add_pp_kernel(float* __restrict__ out,
    const ushort* __restrict__ p0b, const ushort* __restrict__ p1b,
    const float* __restrict__ bias){
  for (int it = 0; it < 4; ++it){
    size_t i4 = (size_t)it * 2048 * 256 + blockIdx.x * 256 + threadIdx.x;
    size_t i = i4 * 4;
    float4 o = *(const float4*)(out + i);
    ushort4 a = *(const ushort4*)(p0b + i);
    ushort4 b = *(const ushort4*)(p1b + i);
    float4 bv = *(const float4*)(bias + ((i4 & 255) * 4));
    o.x += bf2f(a.x) + bf2f(b.x) + bv.x;
    o.y += bf2f(a.y) + bf2f(b.y) + bv.y;
    o.z += bf2f(a.z) + bf2f(b.z) + bv.z;
    o.w += bf2f(a.w) + bf2f(b.w) + bv.w;
    *(float4*)(out + i) = o;
  }
}

// ---------------- LN1 ----------------
__global__ __launch_bounds__(256) void ln1_kernel(const float* __restrict__ x,
    const float* __restrict__ gw, const float* __restrict__ bw,
    ushort* __restrict__ hout){
  int row = blockIdx.x, tid = threadIdx.x;
  size_t base = (size_t)row * Cc + tid * 4;
  float4 xv = *(const float4*)(x + base);
  float s  = xv.x + xv.y + xv.z + xv.w;
  float ss = xv.x*xv.x + xv.y*xv.y + xv.z*xv.z + xv.w*xv.w;
  #pragma unroll
  for (int off = 1; off < 64; off <<= 1){ s += __shfl_xor(s, off); ss += __shfl_xor(ss, off); }
  __shared__ float red[8];
  int wid = tid >> 6, lane = tid & 63;
  if (lane == 0){ red[wid] = s; red[4 + wid] = ss; }
  __syncthreads();
  s  = red[0] + red[1] + red[2] + red[3];
  ss = red[4] + red[5] + red[6] + red[7];
  float mu = s * (1.0f / Cc);
  float rstd = rsqrtf(ss * (1.0f / Cc) - mu * mu + 1e-5f);
  float4 gv = *(const float4*)(gw + tid * 4);
  float4 bv = *(const float4*)(bw + tid * 4);
  ushort4 o;
  o.x = f2bf((xv.x - mu) * rstd * gv.x + bv.x);
  o.y = f2bf((xv.y - mu) * rstd * gv.y + bv.y);
  o.z = f2bf((xv.z - mu) * rstd * gv.z + bv.z);
  o.w = f2bf((xv.w - mu) * rstd * gv.w + bv.w);
  *(ushort4*)(hout + base) = o;
}

// ---------------- LN2: x2 = x + attn -> d_out, h2 = LN(x2) -> bf16 ----------------
__global__ __launch_bounds__(256) void ln2_kernel(const float* __restrict__ x,
    const ushort* __restrict__ attnb,
    const float* __restrict__ gw, const float* __restrict__ bw,
    float* __restrict__ x2, ushort* __restrict__ hout){
  int row = blockIdx.x, tid = threadIdx.x;
  size_t base = (size_t)row * Cc + tid * 4;
  float4 xv = *(const float4*)(x + base);
  ushort4 av = *(const ushort4*)(attnb + base);
  xv.x += bf2f(av.x); xv.y += bf2f(av.y); xv.z += bf2f(av.z); xv.w += bf2f(av.w);
  *(float4*)(x2 + base) = xv;
  float s  = xv.x + xv.y + xv.z + xv.w;
  float ss = xv.x*xv.x + xv.y*xv.y + xv.z*xv.z + xv.w*xv.w;
  #pragma unroll
  for (int off = 1; off < 64; off <<= 1){ s += __shfl_xor(s, off); ss += __shfl_xor(ss, off); }
  __shared__ float red[8];
  int wid = tid >> 6, lane = tid & 63;
  if (lane == 0){ red[wid] = s; red[4 + wid] = ss; }
  __syncthreads();
  s  = red[0] + red[1] + red[2] + red[3];
  ss = red[4] + red[5] + red[6] + red[7];
  float mu = s * (1.0f / Cc);
  float rstd = rsqrtf(ss * (1.0f / Cc) - mu * mu + 1e-5f);
  float4 gv = *(const float4*)(gw + tid * 4);
  float4 bv = *(const float4*)(bw + tid * 4);
  ushort4 o;
  o.x = f2bf((xv.x - mu) * rstd * gv.x + bv.x);
  o.y = f2bf((xv.y - mu) * rstd * gv.y + bv.y);
  o.z = f2bf((xv.z - mu) * rstd * gv.z + bv.z);
  o.w = f2bf((xv.w - mu) * rstd * gv.w + bv.w);
  *(ushort4*)(hout + base) = o;
}

// =====================================================================
// 256x256 GEMM (R13 pipelined structure) — QKV + FFN2.
// MODE 0: QKV scatter (q pre-scaled by 0.125*log2e: softmax scale + exp2 fold).
// MODE 3: split-K=2, both splits store bf16 partials.
// =====================================================================
#define MFMA_QUAD(AF, SI, QI, BQ) \
  { \
    _Pragma("unroll") \
    for (int mi = 0; mi < 4; ++mi){ \
      acc[(SI)*4+mi][(QI)*2+0] = __builtin_amdgcn_mfma_f32_16x16x32_bf16(AF[mi][0], BQ[0][0], acc[(SI)*4+mi][(QI)*2+0], 0,0,0); \
      acc[(SI)*4+mi][(QI)*2+0] = __builtin_amdgcn_mfma_f32_16x16x32_bf16(AF[mi][1], BQ[0][1], acc[(SI)*4+mi][(QI)*2+0], 0,0,0); \
      acc[(SI)*4+mi][(QI)*2+1] = __builtin_amdgcn_mfma_f32_16x16x32_bf16(AF[mi][0], BQ[1][0], acc[(SI)*4+mi][(QI)*2+1], 0,0,0); \
      acc[(SI)*4+mi][(QI)*2+1] = __builtin_amdgcn_mfma_f32_16x16x32_bf16(AF[mi][1], BQ[1][1], acc[(SI)*4+mi][(QI)*2+1], 0,0,0); \
    } \
  }

#define GEMM_TOP() { asm volatile("s_waitcnt lgkmcnt(0)" ::: "memory"); \
                     __builtin_amdgcn_sched_barrier(0); __builtin_amdgcn_s_setprio(1); }
#define GEMM_MID() { __builtin_amdgcn_s_setprio(0); }
#define GEMM_BAR() { __builtin_amdgcn_s_barrier(); }

template<int MODE>
__device__ __forceinline__ void gemm256_body(
    const ushort* __restrict__ A, const ushort* __restrict__ Bw,
    int N, int K, int ldO,
    ushort* __restrict__ obf, float* __restrict__ of32,
    ushort* __restrict__ p1b, const float* __restrict__ bias)
{
  __shared__ __align__(16) ushort lds[2][2][2][128 * 64];  // [buf][A/B][half][128r x 64k]
  int tid = threadIdx.x, lane = tid & 63, wid = tid >> 6;
  int wm = wid >> 2, wn = wid & 3;
  int c = lane & 15, g = lane >> 4;
  int brow0 = (wn & 1) * 64;

  int nwg = gridDim.x, bid = blockIdx.x;
  int wgid = (bid & 7) * (nwg >> 3) + (bid >> 3);
  int m0, n0, koff = 0;
  if (MODE == 3){
    int split = wgid >> 7, rem = wgid & 127;   // 2 x (32 m-tiles x 4 n-tiles)
    m0 = (rem >> 2) << 8; n0 = (rem & 3) << 8; koff = split << 11;
  } else {
    int nTn = N >> 8;
    m0 = (wgid / nTn) << 8; n0 = (wgid % nTn) << 8;
  }

  const ushort* Ag = A  + (size_t)m0 * K + koff;
  const ushort* Bg = Bw + (size_t)n0 * K + koff;

  auto stage = [&](const ushort* gbase, int t, int ab, int hb){
    #pragma unroll
    for (int j = 0; j < 2; ++j){
      int d = j * 8192 + wid * 1024 + lane * 16;
      int row = d >> 7;
      int colb = (d & 127) ^ ((row & 7) << 4);
      gload16((const char*)gbase + ((size_t)(hb * 128 + row) * K + t * 64) * 2 + colb,
              (char*)&lds[t & 1][ab][hb][0] + j * 8192 + wid * 1024);
    }
  };

  f32x4 acc[8][4] = {};
  bf16x8 af0[4][2], af1[4][2], bq0[2][2], bq1[2][2];

  auto readA = [&](const char* Ap, int sub, bf16x8 (&af)[4][2]){
    #pragma unroll
    for (int mi = 0; mi < 4; ++mi){
      int row = sub * 64 + mi * 16 + c, sw = (row & 7) << 4;
      af[mi][0] = *(const bf16x8*)(Ap + row * 128 + ((g * 16) ^ sw));
      af[mi][1] = *(const bf16x8*)(Ap + row * 128 + ((64 + g * 16) ^ sw));
    }
  };
  auto readB = [&](const char* Bp, int hb, bf16x8 (&bq)[2][2]){
    #pragma unroll
    for (int nj = 0; nj < 2; ++nj){
      int row = brow0 + hb * 32 + nj * 16 + c, sw = (row & 7) << 4;
      bq[nj][0] = *(const bf16x8*)(Bp + row * 128 + ((g * 16) ^ sw));
      bq[nj][1] = *(const bf16x8*)(Bp + row * 128 + ((64 + g * 16) ^ sw));
    }
  };

  int nt = (MODE == 3) ? (K >> 7) : (K >> 6);

  // ---- prologue ----
  stage(Ag, 0, 0, 0); stage(Ag, 0, 0, 1);
  stage(Bg, 0, 1, 0); stage(Bg, 0, 1, 1);
  if (nt > 1){
    stage(Bg, 1, 1, 0); stage(Bg, 1, 1, 1);
    stage(Ag, 1, 0, 0); stage(Ag, 1, 0, 1);
    asm volatile("s_waitcnt vmcnt(8)" ::: "memory");
  } else {
    asm volatile("s_waitcnt vmcnt(0)" ::: "memory");
  }
  __builtin_amdgcn_s_barrier();
  readA((const char*)&lds[0][0][wm][0], 0, af0);
  readB((const char*)&lds[0][1][wn >> 1][0], 0, bq0);

  for (int t = 0; t < nt; ++t){
    const char* Abuf  = (const char*)&lds[t & 1][0][wm][0];
    const char* Bbuf  = (const char*)&lds[t & 1][1][wn >> 1][0];
    const char* AbufN = (const char*)&lds[(t + 1) & 1][0][wm][0];
    const char* BbufN = (const char*)&lds[(t + 1) & 1][1][wn >> 1][0];

    GEMM_TOP();
    MFMA_QUAD(af0, 0, 0, bq0);
    GEMM_MID();
    readB(Bbuf, 1, bq1);
    GEMM_BAR();                                  // B1

    GEMM_TOP();
    MFMA_QUAD(af0, 0, 1, bq1);
    GEMM_MID();
    readA(Abuf, 1, af1);
    GEMM_BAR();                                  // B2

    GEMM_TOP();
    MFMA_QUAD(af1, 1, 0, bq0);
    GEMM_MID();
    if (t + 2 < nt){
      stage(Bg, t + 2, 1, 0);
      asm volatile("s_waitcnt vmcnt(2)" ::: "memory");
    } else {
      asm volatile("s_waitcnt vmcnt(0)" ::: "memory");
    }
    GEMM_BAR();                                  // B3 (tile t+1 landed)

    GEMM_TOP();
    MFMA_QUAD(af1, 1, 1, bq1);
    GEMM_MID();
    if (t + 1 < nt){
      readA(AbufN, 0, af0);
      readB(BbufN, 0, bq0);
    }
    if (t + 2 < nt){
      stage(Bg, t + 2, 1, 1);
      stage(Ag, t + 2, 0, 0);
      stage(Ag, t + 2, 0, 1);
    }
    GEMM_BAR();                                  // B4
  }

  #pragma unroll
  for (int mi = 0; mi < 8; ++mi){
    #pragma unroll
    for (int ni = 0; ni < 4; ++ni){
      #pragma unroll
      for (int r = 0; r < 4; ++r){
        float v = acc[mi][ni][r];
        int m = m0 + wm * 128 + mi * 16 + g * 4 + r;
        int n = n0 + wn * 64 + ni * 16 + c;
        if (MODE == 0){
          int which = n >> 10;
          int nn = n & 1023;
          int b = m >> 11, t = m & (Tt - 1);
          int h = nn >> 6, d = nn & 63;
          // q scale = 0.125 (softmax) * log2(e) (exp2 fold in attn)
          float vv = (which == 0) ? v * 0.18033688f : v;
          size_t base = (size_t)which * (size_t)(Bb * Tt * Cc);
          size_t idx = (which == 2)
              ? ((((size_t)(b * Hh + h)) * HSs + d) * Tt + t)     // V^T [B,H,HS,T]
              : ((((size_t)(b * Hh + h)) * Tt + t) * HSs + d);    // Q,K [B,H,T,HS]
          obf[base + idx] = f2bf(vv);
        } else {
          size_t idx = (size_t)m * N + n;
          if (koff == 0) obf[idx] = f2bf(v);    // split 0 partial (bf16)
          else           p1b[idx] = f2bf(v);    // split 1 partial (bf16)
        }
      }
    }
  }
}

__global__ __launch_bounds__(512, 2) void gemm_qkv_kernel(
    const ushort* __restrict__ A, const ushort* __restrict__ Bw, int N, int K,
    ushort* __restrict__ obf){
  gemm256_body<0>(A, Bw, N, K, 0, obf, nullptr, nullptr, nullptr);
}
__global__ __launch_bounds__(512, 2) void gemm_ffn2_kernel(
    const ushort* __restrict__ A, const ushort* __restrict__ Bw, int N, int K,
    ushort* __restrict__ p0b, ushort* __restrict__ p1b){
  gemm256_body<3>(A, Bw, N, K, N, p0b, nullptr, p1b, nullptr);
}

// =====================================================================
// R18 FFN1: m97-style 128x128 tile, 4 waves (2x2), BK=64, dbuf LDS 64KB ->
// 2 blocks/CU (2 independent barrier groups: block-level TLP, m114).
// 1 barrier + 1 vmcnt(0) per K-tile, 32 MFMA between barriers.
// stage(t+1)->buf^1 issued at TOP; vmcnt(0) at BOTTOM covered by 32 MFMA.
// End barrier orders all waves' reads of buf before t+1's stage(t+2) lands.
// =====================================================================
__global__ __launch_bounds__(256, 2) void gemm128_ffn1_kernel(
    const ushort* __restrict__ A, const ushort* __restrict__ Bw,
    int N, int K, int ldO,
    ushort* __restrict__ obf, const float* __restrict__ bias)
{
  __shared__ __align__(16) ushort lds[2][2][128 * 64];   // [buf][A/B] 16KB each
  int tid = threadIdx.x, lane = tid & 63, wid = tid >> 6;
  int wm = wid >> 1, wn = wid & 1;
  int c = lane & 15, g = lane >> 4;

  int nwg = gridDim.x, bid = blockIdx.x;
  int wgid = (bid & 7) * (nwg >> 3) + (bid >> 3);
  int nTn = N >> 7;
  int m0 = (wgid / nTn) << 7, n0 = (wgid % nTn) << 7;

  const ushort* Ag = A  + (size_t)m0 * K;
  const ushort* Bg = Bw + (size_t)n0 * K;

  auto stage = [&](int t, int bsel){
    #pragma unroll
    for (int j = 0; j < 4; ++j){
      int d = j * 4096 + wid * 1024 + lane * 16;
      int row = d >> 7;
      int colb = (d & 127) ^ ((row & 7) << 4);
      gload16((const char*)Ag + ((size_t)row * K + t * 64) * 2 + colb,
              (char*)&lds[bsel][0][0] + j * 4096 + wid * 1024);
      gload16((const char*)Bg + ((size_t)row * K + t * 64) * 2 + colb,
              (char*)&lds[bsel][1][0] + j * 4096 + wid * 1024);
    }
  };

  f32x4 acc[4][4] = {};
  int nt = K >> 6;

  stage(0, 0);
  asm volatile("s_waitcnt vmcnt(0)" ::: "memory");
  __builtin_amdgcn_s_barrier();

  for (int t = 0; t < nt; ++t){
    int buf = t & 1;
    if (t + 1 < nt) stage(t + 1, buf ^ 1);

    const char* Ap = (const char*)&lds[buf][0][0];
    const char* Bp = (const char*)&lds[buf][1][0];
    #pragma unroll
    for (int ks = 0; ks < 2; ++ks){
      bf16x8 af[4], bq[4];
      #pragma unroll
      for (int i = 0; i < 4; ++i){
        int ra = wm * 64 + i * 16 + c;
        af[i] = *(const bf16x8*)(Ap + ra * 128 + ((ks * 64 + g * 16) ^ ((ra & 7) << 4)));
        int rb = wn * 64 + i * 16 + c;
        bq[i] = *(const bf16x8*)(Bp + rb * 128 + ((ks * 64 + g * 16) ^ ((rb & 7) << 4)));
      }
      asm volatile("s_waitcnt lgkmcnt(0)" ::: "memory");
      __builtin_amdgcn_sched_barrier(0);
      __builtin_amdgcn_s_setprio(1);
      #pragma unroll
      for (int mi = 0; mi < 4; ++mi)
        #pragma unroll
        for (int ni = 0; ni < 4; ++ni)
          acc[mi][ni] = __builtin_amdgcn_mfma_f32_16x16x32_bf16(af[mi], bq[ni], acc[mi][ni], 0, 0, 0);
      __builtin_amdgcn_s_setprio(0);
    }

    if (t + 1 < nt) asm volatile("s_waitcnt vmcnt(0)" ::: "memory");
    __builtin_amdgcn_sched_barrier(0);
    __builtin_amdgcn_s_barrier();
  }

  #pragma unroll
  for (int mi = 0; mi < 4; ++mi)
    #pragma unroll
    for (int ni = 0; ni < 4; ++ni)
      #pragma unroll
      for (int r = 0; r < 4; ++r){
        int m = m0 + wm * 64 + mi * 16 + g * 4 + r;
        int n = n0 + wn * 64 + ni * 16 + c;
        float v = acc[mi][ni][r] + bias[n];
        float sv = v / (1.0f + __expf(-v));   // SiLU
        obf[(size_t)m * ldO + n] = f2bf(sv);
      }
}

// ---------------- causal flash attention (R17 + exp2-fold: p = exp2(S)) ----------------
__global__ __launch_bounds__(256, 2) void attn_kernel(
    const ushort* __restrict__ q, const ushort* __restrict__ k,
    const ushort* __restrict__ vt, ushort* __restrict__ attnb)
{
  __shared__ __align__(16) ushort Ksm[4][64 * 64];
  __shared__ __align__(16) ushort Vsm[4][64 * 64];
  __shared__ __align__(16) ushort Pl[4][32 * 64];

  int bh  = blockIdx.y;
  int p   = blockIdx.x;                       // 0..7
  int tid = threadIdx.x, wid = tid >> 6, lane = tid & 63;
  int g = lane >> 4, c = lane & 15;
  int qbA = 15 - p, qbB = p;                  // A = long tile, B = short tile
  int q0A = qbA * 128 + wid * 32;
  int q0B = qbB * 128 + wid * 32;
  const ushort* Qb = q  + (size_t)bh * Tt * HSs;
  const ushort* Kb = k  + (size_t)bh * Tt * HSs;
  const ushort* Vt = vt + (size_t)bh * HSs * Tt;
  char* Pw = (char*)&Pl[wid][0];

  auto stageKV = [&](int bsel, int s0){
    #pragma unroll
    for (int hb = 0; hb < 2; ++hb){
      int i = wid + hb * 4;                   // 0..7
      int row = i * 8 + (lane >> 3);          // 0..63
      int col = ((lane & 7) ^ (row & 7)) * 8; // inverse-swizzled source
      gload16(Kb + (size_t)(s0 + row) * HSs + col, &Ksm[bsel][i * 512]);
      gload16(Vt + (size_t)row * Tt + s0 + col,    &Vsm[bsel][i * 512]);
    }
  };

  bf16x8 qfA[2][2], qfB[2][2];
  #pragma unroll
  for (int mi = 0; mi < 2; ++mi)
    #pragma unroll
    for (int ks = 0; ks < 2; ++ks){
      qfA[mi][ks] = *(const bf16x8*)(Qb + (size_t)(q0A + mi * 16 + c) * HSs + ks * 32 + g * 8);
      qfB[mi][ks] = *(const bf16x8*)(Qb + (size_t)(q0B + mi * 16 + c) * HSs + ks * 32 + g * 8);
    }

  f32x4 oA[2][4] = {}, oB[2][4] = {};
  float lA[2][4] = {}, lB[2][4] = {};

  auto computeTile = [&](bf16x8 (&qf)[2][2], f32x4 (&o)[2][4],
                         float (&lpart)[2][4],
                         int q0w, int s0, const char* Kbuf, const char* Vbuf){
    f32x4 S[2][4] = {};
    bf16x8 kf[4][2];
    #pragma unroll
    for (int ni = 0; ni < 4; ++ni)
      #pragma unroll
      for (int ks = 0; ks < 2; ++ks)
        kf[ni][ks] = *(const bf16x8*)(Kbuf + (ni * 16 + c) * 128 + (((ks * 4 + g) ^ (c & 7)) << 4));
    __builtin_amdgcn_s_setprio(1);
    #pragma unroll
    for (int mi = 0; mi < 2; ++mi)
      #pragma unroll
      for (int ni = 0; ni < 4; ++ni)
        #pragma unroll
        for (int ks = 0; ks < 2; ++ks)
          S[mi][ni] = __builtin_amdgcn_mfma_f32_16x16x32_bf16(qf[mi][ks], kf[ni][ks], S[mi][ni], 0, 0, 0);
    __builtin_amdgcn_s_setprio(0);

    if (s0 + 63 > q0w){   // diagonal chunk: causal mask
      #pragma unroll
      for (int mi = 0; mi < 2; ++mi)
        #pragma unroll
        for (int ni = 0; ni < 4; ++ni)
          #pragma unroll
          for (int r = 0; r < 4; ++r){
            int tl = q0w + mi * 16 + g * 4 + r, sl = s0 + ni * 16 + c;
            if (sl > tl) S[mi][ni][r] = -1e30f;
          }
    }

    // S already includes log2(e) via q pre-scale: p = exp2(S). Masked -> 0.
    #pragma unroll
    for (int mi = 0; mi < 2; ++mi)
      #pragma unroll
      for (int r = 0; r < 4; ++r){
        int row = mi * 16 + g * 4 + r;
        float pp[4];
        #pragma unroll
        for (int ni = 0; ni < 4; ++ni){
          pp[ni] = exp2f(S[mi][ni][r]);
          *(ushort*)(Pw + row * 128 + (((ni * 32 + 2 * c) ^ ((row & 7) << 4)))) = f2bf(pp[ni]);
        }
        lpart[mi][r] += (pp[0] + pp[1]) + (pp[2] + pp[3]);
      }

    bf16x8 vf[4][2];
    #pragma unroll
    for (int dt = 0; dt < 4; ++dt)
      #pragma unroll
      for (int ks = 0; ks < 2; ++ks)
        vf[dt][ks] = *(const bf16x8*)(Vbuf + (dt * 16 + c) * 128 + (((ks * 4 + g) ^ (c & 7)) << 4));
    __builtin_amdgcn_s_setprio(1);
    #pragma unroll
    for (int mi = 0; mi < 2; ++mi){
      #pragma unroll
      for (int ks = 0; ks < 2; ++ks){
        bf16x8 pf = *(const bf16x8*)(Pw + (mi * 16 + c) * 128 + ((((ks * 4 + g) ^ (c & 7)) << 4)));
        #pragma unroll
        for (int dt = 0; dt < 4; ++dt)
          o[mi][dt] = __builtin_amdgcn_mfma_f32_16x16x32_bf16(pf, vf[dt][ks], o[mi][dt], 0, 0, 0);
      }
    }
    __builtin_amdgcn_s_setprio(0);
  };

  int nchA = 2 * qbA + 2;                     // even, >= 18

  stageKV(0, 0);
  stageKV(1, 64);

  for (int ch = 0; ch < nchA; ch += 2){
    bool staged = (ch + 2 < nchA);
    if (staged){
      stageKV((ch + 2) & 3, (ch + 2) * 64);
      stageKV((ch + 3) & 3, (ch + 3) * 64);
      asm volatile("s_waitcnt vmcnt(8)" ::: "memory");   // (ch,ch+1) landed
    } else {
      asm volatile("s_waitcnt vmcnt(0)" ::: "memory");
    }
    __builtin_amdgcn_sched_barrier(0);
    __builtin_amdgcn_s_barrier();

    {
      int s0 = ch * 64;
      const char* Kbuf = (const char*)&Ksm[ch & 3][0];
      const char* Vbuf = (const char*)&Vsm[ch & 3][0];
      if (s0 <= q0A + 31) computeTile(qfA, oA, lA, q0A, s0, Kbuf, Vbuf);
      if (s0 <= q0B + 31) computeTile(qfB, oB, lB, q0B, s0, Kbuf, Vbuf);
    }
    {
      int s0 = (ch + 1) * 64;
      const char* Kbuf = (const char*)&Ksm[(ch + 1) & 3][0];
      const char* Vbuf = (const char*)&Vsm[(ch + 1) & 3][0];
      if (s0 <= q0A + 31) computeTile(qfA, oA, lA, q0A, s0, Kbuf, Vbuf);
      if (s0 <= q0B + 31) computeTile(qfB, oB, lB, q0B, s0, Kbuf, Vbuf);
    }

    __builtin_amdgcn_sched_barrier(0);
    __builtin_amdgcn_s_barrier();             // reads done before next-iter stages
  }

  int b = bh >> 4, h = bh & 15;
  #pragma unroll
  for (int mi = 0; mi < 2; ++mi)
    #pragma unroll
    for (int r = 0; r < 4; ++r){
      float la = lA[mi][r];
      la += __shfl_xor(la, 1); la += __shfl_xor(la, 2);
      la += __shfl_xor(la, 4); la += __shfl_xor(la, 8);
      float lia = 1.0f / la;
      float lb = lB[mi][r];
      lb += __shfl_xor(lb, 1); lb += __shfl_xor(lb, 2);
      lb += __shfl_xor(lb, 4); lb += __shfl_xor(lb, 8);
      float lib = 1.0f / lb;
      #pragma unroll
      for (int dt = 0; dt < 4; ++dt){
        int tA = q0A + mi * 16 + g * 4 + r;
        int tB = q0B + mi * 16 + g * 4 + r;
        attnb[((size_t)(b * Tt + tA)) * Cc + h * HSs + dt * 16 + c] = f2bf(oA[mi][dt][r] * lia);
        attnb[((size_t)(b * Tt + tB)) * Cc + h * HSs + dt * 16 + c] = f2bf(oB[mi][dt][r] * lib);
      }
    }
}

extern "C" void kernel_launch(void* const* d_in, const int* in_sizes, int n_in,
                              void* d_out, int out_size, void* d_ws, size_t ws_size,
                              hipStream_t stream) {
  (void)in_sizes; (void)n_in; (void)out_size; (void)ws_size;
  const float* x    = (const float*)d_in[0];
  const float* wq   = (const float*)d_in[2];
  const float* wk   = (const float*)d_in[3];
  const float* wv   = (const float*)d_in[4];
  const float* ln1g = (const float*)d_in[5];
  const float* ln1b = (const float*)d_in[6];
  const float* ln2g = (const float*)d_in[7];
  const float* ln2b = (const float*)d_in[8];
  const float* w1   = (const float*)d_in[9];
  const float* b1   = (const float*)d_in[10];
  const float* w2   = (const float*)d_in[11];
  const float* b2   = (const float*)d_in[12];
  float* out = (float*)d_out;

  char* ws = (char*)d_ws;
  const size_t SZ_ACT = (size_t)Bb * Tt * Cc * 2;
  ushort* h1    = (ushort*)(ws);
  ushort* qbuf  = (ushort*)(ws + SZ_ACT);
  ushort* kbuf  = (ushort*)(ws + 2 * SZ_ACT);
  ushort* vbuf  = (ushort*)(ws + 3 * SZ_ACT);   // V^T [B,H,HS,T]
  ushort* attnb = (ushort*)(ws + 4 * SZ_ACT);
  ushort* h2    = (ushort*)(ws + 5 * SZ_ACT);
  ushort* h3    = (ushort*)(ws + 6 * SZ_ACT);
  ushort* p0b   = (ushort*)(ws + SZ_ACT);       // bf16 partials in dead q/k bufs
  ushort* p1b   = (ushort*)(ws + 2 * SZ_ACT);
  char*   wsw   = ws + 6 * SZ_ACT + (size_t)Bb * Tt * 4 * Cc * 2;
  ushort* wqb = (ushort*)(wsw);                 // wq,wk,wv,w1,w2 contiguous bf16
  ushort* w1b = (ushort*)(wsw + 3 * (size_t)Cc * Cc * 2);
  ushort* w2b = (ushort*)(wsw + 3 * (size_t)Cc * Cc * 2 + (size_t)4 * Cc * Cc * 2);

  cast_all_kernel<<<dim3(11264), 256, 0, stream>>>(wq, wk, wv, w1, w2, wqb);

  ln1_kernel<<<dim3(Bb * Tt), 256, 0, stream>>>(x, ln1g, ln1b, h1);

  // fused QKV projection: [8192,3072] = h1 @ [3072,1024]^T
  gemm_qkv_kernel<<<dim3(32 * 12), 512, 0, stream>>>(h1, wqb, 3 * Cc, Cc, qbuf);

  attn_kernel<<<dim3(8, Bb * Hh), 256, 0, stream>>>(qbuf, kbuf, vbuf, attnb);

  ln2_kernel<<<dim3(Bb * Tt), 256, 0, stream>>>(x, attnb, ln2g, ln2b, out, h2);

  // FFN1: m97-style 128^2 kernel, 2048 blocks (2 blocks/CU), SiLU epilogue
  gemm128_ffn1_kernel<<<dim3(2048), 256, 0, stream>>>(h2, w1b, 4 * Cc, Cc, 4 * Cc, h3, b1);
  // FFN2: split-K=2 (256 blocks); both splits -> bf16 partials
  gemm_ffn2_kernel<<<dim3(256), 512, 0, stream>>>(h3, w2b, Cc, 4 * Cc, p0b, p1b);
  // out += p0 + p1 + bias
  add_pp_kernel<<<dim3(2048), 256, 0, stream>>>(out, p0b, p1b, b2);
}

// Round 19
// 360.075 us; speedup vs baseline: 1.0384x; 1.0384x over previous
//
#include <hip/hip_runtime.h>
#include <stdint.h>

#define Bb 4
#define Tt 2048
#define Cc 1024
#define Hh 16
#define HSs 64

typedef __attribute__((ext_vector_type(8))) __bf16 bf16x8;
typedef __attribute__((ext_vector_type(4))) float f32x4;

// round-half-up bf16 cast: 2 VALU ops (vs 4 for RNE). Ties differ from RNE only.
__device__ __forceinline__ ushort f2bf(float f){
  union { float f; uint u; } c; c.f = f;
  return (ushort)((c.u + 0x8000u) >> 16);
}
__device__ __forceinline__ float bf2f(ushort u){
  union { uint u; float f; } c; c.u = ((uint)u) << 16; return c.f;
}

// async global->LDS, 16B per lane. LDS dest wave-uniform base; HW adds lane*16.
__device__ __forceinline__ void gload16(const void* g, void* l){
  __builtin_amdgcn_global_load_lds(
      (__attribute__((address_space(1))) void*)(g),
      (__attribute__((address_space(3))) void*)(l), 16, 0, 0);
}

// ---------------- merged fp32 -> bf16 weight cast ----------------
__global__ __launch_bounds__(256) void cast_all_kernel(
    const float* __restrict__ wq, const float* __restrict__ wk,
    const float* __restrict__ wv, const float* __restrict__ w1,
    const float* __restrict__ w2, ushort* __restrict__ out){
  int i = (blockIdx.x * 256 + threadIdx.x) * 4;
  const float* src; int off;
  if      (i <  1048576){ src = wq; off = i; }
  else if (i <  2097152){ src = wk; off = i - 1048576; }
  else if (i <  3145728){ src = wv; off = i - 2097152; }
  else if (i <  7340032){ src = w1; off = i - 3145728; }
  else                  { src = w2; off = i - 7340032; }
  float4 v = *(const float4*)(src + off);
  ushort4 o; o.x = f2bf(v.x); o.y = f2bf(v.y); o.z = f2bf(v.z); o.w = f2bf(v.w);
  *(ushort4*)(out + i) = o;
}

// ---------------- FFN2 finish: out += p0 + p1 + bias ----------------
__global__ __launch_bounds__(256) void add_pp_kernel(float* __restrict__ out,
    const ushort* __restrict__ p0b, const ushort* __restrict__ p1b,
    const float* __restrict__ bias){
  for (int it = 0; it < 4; ++it){
    size_t i4 = (size_t)it * 2048 * 256 + blockIdx.x * 256 + threadIdx.x;
    size_t i = i4 * 4;
    float4 o = *(const float4*)(out + i);
    ushort4 a = *(const ushort4*)(p0b + i);
    ushort4 b = *(const ushort4*)(p1b + i);
    float4 bv = *(const float4*)(bias + ((i4 & 255) * 4));
    o.x += bf2f(a.x) + bf2f(b.x) + bv.x;
    o.y += bf2f(a.y) + bf2f(b.y) + bv.y;
    o.z += bf2f(a.z) + bf2f(b.z) + bv.z;
    o.w += bf2f(a.w) + bf2f(b.w) + bv.w;
    *(float4*)(out + i) = o;
  }
}

// ---------------- LN1 ----------------
__global__ __launch_bounds__(256) void ln1_kernel(const float* __restrict__ x,
    const float* __restrict__ gw, const float* __restrict__ bw,
    ushort* __restrict__ hout){
  int row = blockIdx.x, tid = threadIdx.x;
  size_t base = (size_t)row * Cc + tid * 4;
  float4 xv = *(const float4*)(x + base);
  float s  = xv.x + xv.y + xv.z + xv.w;
  float ss = xv.x*xv.x + xv.y*xv.y + xv.z*xv.z + xv.w*xv.w;
  #pragma unroll
  for (int off = 1; off < 64; off <<= 1){ s += __shfl_xor(s, off); ss += __shfl_xor(ss, off); }
  __shared__ float red[8];
  int wid = tid >> 6, lane = tid & 63;
  if (lane == 0){ red[wid] = s; red[4 + wid] = ss; }
  __syncthreads();
  s  = red[0] + red[1] + red[2] + red[3];
  ss = red[4] + red[5] + red[6] + red[7];
  float mu = s * (1.0f / Cc);
  float rstd = rsqrtf(ss * (1.0f / Cc) - mu * mu + 1e-5f);
  float4 gv = *(const float4*)(gw + tid * 4);
  float4 bv = *(const float4*)(bw + tid * 4);
  ushort4 o;
  o.x = f2bf((xv.x - mu) * rstd * gv.x + bv.x);
  o.y = f2bf((xv.y - mu) * rstd * gv.y + bv.y);
  o.z = f2bf((xv.z - mu) * rstd * gv.z + bv.z);
  o.w = f2bf((xv.w - mu) * rstd * gv.w + bv.w);
  *(ushort4*)(hout + base) = o;
}

// ---------------- LN2: x2 = x + attn -> d_out, h2 = LN(x2) -> bf16 ----------------
__global__ __launch_bounds__(256) void ln2_kernel(const float* __restrict__ x,
    const ushort* __restrict__ attnb,
    const float* __restrict__ gw, const float* __restrict__ bw,
    float* __restrict__ x2, ushort* __restrict__ hout){
  int row = blockIdx.x, tid = threadIdx.x;
  size_t base = (size_t)row * Cc + tid * 4;
  float4 xv = *(const float4*)(x + base);
  ushort4 av = *(const ushort4*)(attnb + base);
  xv.x += bf2f(av.x); xv.y += bf2f(av.y); xv.z += bf2f(av.z); xv.w += bf2f(av.w);
  *(float4*)(x2 + base) = xv;
  float s  = xv.x + xv.y + xv.z + xv.w;
  float ss = xv.x*xv.x + xv.y*xv.y + xv.z*xv.z + xv.w*xv.w;
  #pragma unroll
  for (int off = 1; off < 64; off <<= 1){ s += __shfl_xor(s, off); ss += __shfl_xor(ss, off); }
  __shared__ float red[8];
  int wid = tid >> 6, lane = tid & 63;
  if (lane == 0){ red[wid] = s; red[4 + wid] = ss; }
  __syncthreads();
  s  = red[0] + red[1] + red[2] + red[3];
  ss = red[4] + red[5] + red[6] + red[7];
  float mu = s * (1.0f / Cc);
  float rstd = rsqrtf(ss * (1.0f / Cc) - mu * mu + 1e-5f);
  float4 gv = *(const float4*)(gw + tid * 4);
  float4 bv = *(const float4*)(bw + tid * 4);
  ushort4 o;
  o.x = f2bf((xv.x - mu) * rstd * gv.x + bv.x);
  o.y = f2bf((xv.y - mu) * rstd * gv.y + bv.y);
  o.z = f2bf((xv.z - mu) * rstd * gv.z + bv.z);
  o.w = f2bf((xv.w - mu) * rstd * gv.w + bv.w);
  *(ushort4*)(hout + base) = o;
}

// =====================================================================
// 256x256 GEMM (R13 pipelined structure, best measured):
// MODE 0: QKV scatter (q pre-scaled by 0.125*log2e). MODE 1: SiLU+bias bf16.
// MODE 3: split-K=2, both splits store bf16 partials.
// =====================================================================
#define MFMA_QUAD(AF, SI, QI, BQ) \
  { \
    _Pragma("unroll") \
    for (int mi = 0; mi < 4; ++mi){ \
      acc[(SI)*4+mi][(QI)*2+0] = __builtin_amdgcn_mfma_f32_16x16x32_bf16(AF[mi][0], BQ[0][0], acc[(SI)*4+mi][(QI)*2+0], 0,0,0); \
      acc[(SI)*4+mi][(QI)*2+0] = __builtin_amdgcn_mfma_f32_16x16x32_bf16(AF[mi][1], BQ[0][1], acc[(SI)*4+mi][(QI)*2+0], 0,0,0); \
      acc[(SI)*4+mi][(QI)*2+1] = __builtin_amdgcn_mfma_f32_16x16x32_bf16(AF[mi][0], BQ[1][0], acc[(SI)*4+mi][(QI)*2+1], 0,0,0); \
      acc[(SI)*4+mi][(QI)*2+1] = __builtin_amdgcn_mfma_f32_16x16x32_bf16(AF[mi][1], BQ[1][1], acc[(SI)*4+mi][(QI)*2+1], 0,0,0); \
    } \
  }

#define GEMM_TOP() { asm volatile("s_waitcnt lgkmcnt(0)" ::: "memory"); \
                     __builtin_amdgcn_sched_barrier(0); __builtin_amdgcn_s_setprio(1); }
#define GEMM_MID() { __builtin_amdgcn_s_setprio(0); }
#define GEMM_BAR() { __builtin_amdgcn_s_barrier(); }

template<int MODE>
__device__ __forceinline__ void gemm256_body(
    const ushort* __restrict__ A, const ushort* __restrict__ Bw,
    int N, int K, int ldO,
    ushort* __restrict__ obf, float* __restrict__ of32,
    ushort* __restrict__ p1b, const float* __restrict__ bias)
{
  __shared__ __align__(16) ushort lds[2][2][2][128 * 64];  // [buf][A/B][half][128r x 64k]
  int tid = threadIdx.x, lane = tid & 63, wid = tid >> 6;
  int wm = wid >> 2, wn = wid & 3;
  int c = lane & 15, g = lane >> 4;
  int brow0 = (wn & 1) * 64;

  int nwg = gridDim.x, bid = blockIdx.x;
  int wgid = (bid & 7) * (nwg >> 3) + (bid >> 3);
  int m0, n0, koff = 0;
  if (MODE == 3){
    int split = wgid >> 7, rem = wgid & 127;   // 2 x (32 m-tiles x 4 n-tiles)
    m0 = (rem >> 2) << 8; n0 = (rem & 3) << 8; koff = split << 11;
  } else {
    int nTn = N >> 8;
    m0 = (wgid / nTn) << 8; n0 = (wgid % nTn) << 8;
  }

  const ushort* Ag = A  + (size_t)m0 * K + koff;
  const ushort* Bg = Bw + (size_t)n0 * K + koff;

  auto stage = [&](const ushort* gbase, int t, int ab, int hb){
    #pragma unroll
    for (int j = 0; j < 2; ++j){
      int d = j * 8192 + wid * 1024 + lane * 16;
      int row = d >> 7;
      int colb = (d & 127) ^ ((row & 7) << 4);
      gload16((const char*)gbase + ((size_t)(hb * 128 + row) * K + t * 64) * 2 + colb,
              (char*)&lds[t & 1][ab][hb][0] + j * 8192 + wid * 1024);
    }
  };

  f32x4 acc[8][4] = {};
  bf16x8 af0[4][2], af1[4][2], bq0[2][2], bq1[2][2];

  auto readA = [&](const char* Ap, int sub, bf16x8 (&af)[4][2]){
    #pragma unroll
    for (int mi = 0; mi < 4; ++mi){
      int row = sub * 64 + mi * 16 + c, sw = (row & 7) << 4;
      af[mi][0] = *(const bf16x8*)(Ap + row * 128 + ((g * 16) ^ sw));
      af[mi][1] = *(const bf16x8*)(Ap + row * 128 + ((64 + g * 16) ^ sw));
    }
  };
  auto readB = [&](const char* Bp, int hb, bf16x8 (&bq)[2][2]){
    #pragma unroll
    for (int nj = 0; nj < 2; ++nj){
      int row = brow0 + hb * 32 + nj * 16 + c, sw = (row & 7) << 4;
      bq[nj][0] = *(const bf16x8*)(Bp + row * 128 + ((g * 16) ^ sw));
      bq[nj][1] = *(const bf16x8*)(Bp + row * 128 + ((64 + g * 16) ^ sw));
    }
  };

  int nt = (MODE == 3) ? (K >> 7) : (K >> 6);

  // ---- prologue ----
  stage(Ag, 0, 0, 0); stage(Ag, 0, 0, 1);
  stage(Bg, 0, 1, 0); stage(Bg, 0, 1, 1);
  if (nt > 1){
    stage(Bg, 1, 1, 0); stage(Bg, 1, 1, 1);
    stage(Ag, 1, 0, 0); stage(Ag, 1, 0, 1);
    asm volatile("s_waitcnt vmcnt(8)" ::: "memory");
  } else {
    asm volatile("s_waitcnt vmcnt(0)" ::: "memory");
  }
  __builtin_amdgcn_s_barrier();
  readA((const char*)&lds[0][0][wm][0], 0, af0);
  readB((const char*)&lds[0][1][wn >> 1][0], 0, bq0);

  for (int t = 0; t < nt; ++t){
    const char* Abuf  = (const char*)&lds[t & 1][0][wm][0];
    const char* Bbuf  = (const char*)&lds[t & 1][1][wn >> 1][0];
    const char* AbufN = (const char*)&lds[(t + 1) & 1][0][wm][0];
    const char* BbufN = (const char*)&lds[(t + 1) & 1][1][wn >> 1][0];

    GEMM_TOP();
    MFMA_QUAD(af0, 0, 0, bq0);
    GEMM_MID();
    readB(Bbuf, 1, bq1);
    GEMM_BAR();                                  // B1

    GEMM_TOP();
    MFMA_QUAD(af0, 0, 1, bq1);
    GEMM_MID();
    readA(Abuf, 1, af1);
    GEMM_BAR();                                  // B2

    GEMM_TOP();
    MFMA_QUAD(af1, 1, 0, bq0);
    GEMM_MID();
    if (t + 2 < nt){
      stage(Bg, t + 2, 1, 0);
      asm volatile("s_waitcnt vmcnt(2)" ::: "memory");
    } else {
      asm volatile("s_waitcnt vmcnt(0)" ::: "memory");
    }
    GEMM_BAR();                                  // B3 (tile t+1 landed)

    GEMM_TOP();
    MFMA_QUAD(af1, 1, 1, bq1);
    GEMM_MID();
    if (t + 1 < nt){
      readA(AbufN, 0, af0);
      readB(BbufN, 0, bq0);
    }
    if (t + 2 < nt){
      stage(Bg, t + 2, 1, 1);
      stage(Ag, t + 2, 0, 0);
      stage(Ag, t + 2, 0, 1);
    }
    GEMM_BAR();                                  // B4
  }

  #pragma unroll
  for (int mi = 0; mi < 8; ++mi){
    #pragma unroll
    for (int ni = 0; ni < 4; ++ni){
      #pragma unroll
      for (int r = 0; r < 4; ++r){
        float v = acc[mi][ni][r];
        int m = m0 + wm * 128 + mi * 16 + g * 4 + r;
        int n = n0 + wn * 64 + ni * 16 + c;
        if (MODE == 0){
          int which = n >> 10;
          int nn = n & 1023;
          int b = m >> 11, t = m & (Tt - 1);
          int h = nn >> 6, d = nn & 63;
          // q scale = 0.125 (softmax) * log2(e) (exp2 fold in attn)
          float vv = (which == 0) ? v * 0.18033688f : v;
          size_t base = (size_t)which * (size_t)(Bb * Tt * Cc);
          size_t idx = (which == 2)
              ? ((((size_t)(b * Hh + h)) * HSs + d) * Tt + t)     // V^T [B,H,HS,T]
              : ((((size_t)(b * Hh + h)) * Tt + t) * HSs + d);    // Q,K [B,H,T,HS]
          obf[base + idx] = f2bf(vv);
        } else if (MODE == 1){
          v += bias[n];
          float sv = v / (1.0f + __expf(-v));   // SiLU
          obf[(size_t)m * ldO + n] = f2bf(sv);
        } else {
          size_t idx = (size_t)m * N + n;
          if (koff == 0) obf[idx] = f2bf(v);    // split 0 partial (bf16)
          else           p1b[idx] = f2bf(v);    // split 1 partial (bf16)
        }
      }
    }
  }
}

__global__ __launch_bounds__(512, 2) void gemm_qkv_kernel(
    const ushort* __restrict__ A, const ushort* __restrict__ Bw, int N, int K,
    ushort* __restrict__ obf){
  gemm256_body<0>(A, Bw, N, K, 0, obf, nullptr, nullptr, nullptr);
}
__global__ __launch_bounds__(512, 2) void gemm_ffn1_kernel(
    const ushort* __restrict__ A, const ushort* __restrict__ Bw, int N, int K, int ldO,
    ushort* __restrict__ obf, const float* __restrict__ bias){
  gemm256_body<1>(A, Bw, N, K, ldO, obf, nullptr, nullptr, bias);
}
__global__ __launch_bounds__(512, 2) void gemm_ffn2_kernel(
    const ushort* __restrict__ A, const ushort* __restrict__ Bw, int N, int K,
    ushort* __restrict__ p0b, ushort* __restrict__ p1b){
  gemm256_body<3>(A, Bw, N, K, N, p0b, nullptr, p1b, nullptr);
}

// ---------------- causal flash attention (ring-4, pair-chunk, vmcnt(8);
// no-shift softmax with exp2 folded into q pre-scale; setprio on MFMA) ----------------
__global__ __launch_bounds__(256, 2) void attn_kernel(
    const ushort* __restrict__ q, const ushort* __restrict__ k,
    const ushort* __restrict__ vt, ushort* __restrict__ attnb)
{
  __shared__ __align__(16) ushort Ksm[4][64 * 64];
  __shared__ __align__(16) ushort Vsm[4][64 * 64];
  __shared__ __align__(16) ushort Pl[4][32 * 64];

  int bh  = blockIdx.y;
  int p   = blockIdx.x;                       // 0..7
  int tid = threadIdx.x, wid = tid >> 6, lane = tid & 63;
  int g = lane >> 4, c = lane & 15;
  int qbA = 15 - p, qbB = p;                  // A = long tile, B = short tile
  int q0A = qbA * 128 + wid * 32;
  int q0B = qbB * 128 + wid * 32;
  const ushort* Qb = q  + (size_t)bh * Tt * HSs;
  const ushort* Kb = k  + (size_t)bh * Tt * HSs;
  const ushort* Vt = vt + (size_t)bh * HSs * Tt;
  char* Pw = (char*)&Pl[wid][0];

  auto stageKV = [&](int bsel, int s0){
    #pragma unroll
    for (int hb = 0; hb < 2; ++hb){
      int i = wid + hb * 4;                   // 0..7
      int row = i * 8 + (lane >> 3);          // 0..63
      int col = ((lane & 7) ^ (row & 7)) * 8; // inverse-swizzled source
      gload16(Kb + (size_t)(s0 + row) * HSs + col, &Ksm[bsel][i * 512]);
      gload16(Vt + (size_t)row * Tt + s0 + col,    &Vsm[bsel][i * 512]);
    }
  };

  bf16x8 qfA[2][2], qfB[2][2];
  #pragma unroll
  for (int mi = 0; mi < 2; ++mi)
    #pragma unroll
    for (int ks = 0; ks < 2; ++ks){
      qfA[mi][ks] = *(const bf16x8*)(Qb + (size_t)(q0A + mi * 16 + c) * HSs + ks * 32 + g * 8);
      qfB[mi][ks] = *(const bf16x8*)(Qb + (size_t)(q0B + mi * 16 + c) * HSs + ks * 32 + g * 8);
    }

  f32x4 oA[2][4] = {}, oB[2][4] = {};
  float lA[2][4] = {}, lB[2][4] = {};

  auto computeTile = [&](bf16x8 (&qf)[2][2], f32x4 (&o)[2][4],
                         float (&lpart)[2][4],
                         int q0w, int s0, const char* Kbuf, const char* Vbuf){
    f32x4 S[2][4] = {};
    bf16x8 kf[4][2];
    #pragma unroll
    for (int ni = 0; ni < 4; ++ni)
      #pragma unroll
      for (int ks = 0; ks < 2; ++ks)
        kf[ni][ks] = *(const bf16x8*)(Kbuf + (ni * 16 + c) * 128 + (((ks * 4 + g) ^ (c & 7)) << 4));
    __builtin_amdgcn_s_setprio(1);
    #pragma unroll
    for (int mi = 0; mi < 2; ++mi)
      #pragma unroll
      for (int ni = 0; ni < 4; ++ni)
        #pragma unroll
        for (int ks = 0; ks < 2; ++ks)
          S[mi][ni] = __builtin_amdgcn_mfma_f32_16x16x32_bf16(qf[mi][ks], kf[ni][ks], S[mi][ni], 0, 0, 0);
    __builtin_amdgcn_s_setprio(0);

    if (s0 + 63 > q0w){   // diagonal chunk: causal mask
      #pragma unroll
      for (int mi = 0; mi < 2; ++mi)
        #pragma unroll
        for (int ni = 0; ni < 4; ++ni)
          #pragma unroll
          for (int r = 0; r < 4; ++r){
            int tl = q0w + mi * 16 + g * 4 + r, sl = s0 + ni * 16 + c;
            if (sl > tl) S[mi][ni][r] = -1e30f;
          }
    }

    // S already includes log2(e) via q pre-scale: p = exp2(S). Masked -> 0.
    #pragma unroll
    for (int mi = 0; mi < 2; ++mi)
      #pragma unroll
      for (int r = 0; r < 4; ++r){
        int row = mi * 16 + g * 4 + r;
        float pp[4];
        #pragma unroll
        for (int ni = 0; ni < 4; ++ni){
          pp[ni] = exp2f(S[mi][ni][r]);
          *(ushort*)(Pw + row * 128 + (((ni * 32 + 2 * c) ^ ((row & 7) << 4)))) = f2bf(pp[ni]);
        }
        lpart[mi][r] += (pp[0] + pp[1]) + (pp[2] + pp[3]);
      }

    bf16x8 vf[4][2];
    #pragma unroll
    for (int dt = 0; dt < 4; ++dt)
      #pragma unroll
      for (int ks = 0; ks < 2; ++ks)
        vf[dt][ks] = *(const bf16x8*)(Vbuf + (dt * 16 + c) * 128 + (((ks * 4 + g) ^ (c & 7)) << 4));
    __builtin_amdgcn_s_setprio(1);
    #pragma unroll
    for (int mi = 0; mi < 2; ++mi){
      #pragma unroll
      for (int ks = 0; ks < 2; ++ks){
        bf16x8 pf = *(const bf16x8*)(Pw + (mi * 16 + c) * 128 + ((((ks * 4 + g) ^ (c & 7)) << 4)));
        #pragma unroll
        for (int dt = 0; dt < 4; ++dt)
          o[mi][dt] = __builtin_amdgcn_mfma_f32_16x16x32_bf16(pf, vf[dt][ks], o[mi][dt], 0, 0, 0);
      }
    }
    __builtin_amdgcn_s_setprio(0);
  };

  int nchA = 2 * qbA + 2;                     // even, >= 18

  stageKV(0, 0);
  stageKV(1, 64);

  for (int ch = 0; ch < nchA; ch += 2){
    bool staged = (ch + 2 < nchA);
    if (staged){
      stageKV((ch + 2) & 3, (ch + 2) * 64);
      stageKV((ch + 3) & 3, (ch + 3) * 64);
      asm volatile("s_waitcnt vmcnt(8)" ::: "memory");   // (ch,ch+1) landed
    } else {
      asm volatile("s_waitcnt vmcnt(0)" ::: "memory");
    }
    __builtin_amdgcn_sched_barrier(0);
    __builtin_amdgcn_s_barrier();

    {
      int s0 = ch * 64;
      const char* Kbuf = (const char*)&Ksm[ch & 3][0];
      const char* Vbuf = (const char*)&Vsm[ch & 3][0];
      if (s0 <= q0A + 31) computeTile(qfA, oA, lA, q0A, s0, Kbuf, Vbuf);
      if (s0 <= q0B + 31) computeTile(qfB, oB, lB, q0B, s0, Kbuf, Vbuf);
    }
    {
      int s0 = (ch + 1) * 64;
      const char* Kbuf = (const char*)&Ksm[(ch + 1) & 3][0];
      const char* Vbuf = (const char*)&Vsm[(ch + 1) & 3][0];
      if (s0 <= q0A + 31) computeTile(qfA, oA, lA, q0A, s0, Kbuf, Vbuf);
      if (s0 <= q0B + 31) computeTile(qfB, oB, lB, q0B, s0, Kbuf, Vbuf);
    }

    __builtin_amdgcn_sched_barrier(0);
    __builtin_amdgcn_s_barrier();             // reads done before next-iter stages
  }

  int b = bh >> 4, h = bh & 15;
  #pragma unroll
  for (int mi = 0; mi < 2; ++mi)
    #pragma unroll
    for (int r = 0; r < 4; ++r){
      float la = lA[mi][r];
      la += __shfl_xor(la, 1); la += __shfl_xor(la, 2);
      la += __shfl_xor(la, 4); la += __shfl_xor(la, 8);
      float lia = 1.0f / la;
      float lb = lB[mi][r];
      lb += __shfl_xor(lb, 1); lb += __shfl_xor(lb, 2);
      lb += __shfl_xor(lb, 4); lb += __shfl_xor(lb, 8);
      float lib = 1.0f / lb;
      #pragma unroll
      for (int dt = 0; dt < 4; ++dt){
        int tA = q0A + mi * 16 + g * 4 + r;
        int tB = q0B + mi * 16 + g * 4 + r;
        attnb[((size_t)(b * Tt + tA)) * Cc + h * HSs + dt * 16 + c] = f2bf(oA[mi][dt][r] * lia);
        attnb[((size_t)(b * Tt + tB)) * Cc + h * HSs + dt * 16 + c] = f2bf(oB[mi][dt][r] * lib);
      }
    }
}

extern "C" void kernel_launch(void* const* d_in, const int* in_sizes, int n_in,
                              void* d_out, int out_size, void* d_ws, size_t ws_size,
                              hipStream_t stream) {
  (void)in_sizes; (void)n_in; (void)out_size; (void)ws_size;
  const float* x    = (const float*)d_in[0];
  const float* wq   = (const float*)d_in[2];
  const float* wk   = (const float*)d_in[3];
  const float* wv   = (const float*)d_in[4];
  const float* ln1g = (const float*)d_in[5];
  const float* ln1b = (const float*)d_in[6];
  const float* ln2g = (const float*)d_in[7];
  const float* ln2b = (const float*)d_in[8];
  const float* w1   = (const float*)d_in[9];
  const float* b1   = (const float*)d_in[10];
  const float* w2   = (const float*)d_in[11];
  const float* b2   = (const float*)d_in[12];
  float* out = (float*)d_out;

  char* ws = (char*)d_ws;
  const size_t SZ_ACT = (size_t)Bb * Tt * Cc * 2;
  ushort* h1    = (ushort*)(ws);
  ushort* qbuf  = (ushort*)(ws + SZ_ACT);
  ushort* kbuf  = (ushort*)(ws + 2 * SZ_ACT);
  ushort* vbuf  = (ushort*)(ws + 3 * SZ_ACT);   // V^T [B,H,HS,T]
  ushort* attnb = (ushort*)(ws + 4 * SZ_ACT);
  ushort* h2    = (ushort*)(ws + 5 * SZ_ACT);
  ushort* h3    = (ushort*)(ws + 6 * SZ_ACT);
  ushort* p0b   = (ushort*)(ws + SZ_ACT);       // bf16 partials in dead q/k bufs
  ushort* p1b   = (ushort*)(ws + 2 * SZ_ACT);
  char*   wsw   = ws + 6 * SZ_ACT + (size_t)Bb * Tt * 4 * Cc * 2;
  ushort* wqb = (ushort*)(wsw);                 // wq,wk,wv,w1,w2 contiguous bf16
  ushort* w1b = (ushort*)(wsw + 3 * (size_t)Cc * Cc * 2);
  ushort* w2b = (ushort*)(wsw + 3 * (size_t)Cc * Cc * 2 + (size_t)4 * Cc * Cc * 2);

  cast_all_kernel<<<dim3(11264), 256, 0, stream>>>(wq, wk, wv, w1, w2, wqb);

  ln1_kernel<<<dim3(Bb * Tt), 256, 0, stream>>>(x, ln1g, ln1b, h1);

  // fused QKV projection: [8192,3072] = h1 @ [3072,1024]^T
  gemm_qkv_kernel<<<dim3(32 * 12), 512, 0, stream>>>(h1, wqb, 3 * Cc, Cc, qbuf);

  attn_kernel<<<dim3(8, Bb * Hh), 256, 0, stream>>>(qbuf, kbuf, vbuf, attnb);

  ln2_kernel<<<dim3(Bb * Tt), 256, 0, stream>>>(x, attnb, ln2g, ln2b, out, h2);

  // FFN1: single dispatch, [8192,4096] = h2 @ w1^T (512 blocks = 2 rounds)
  gemm_ffn1_kernel<<<dim3(32 * 16), 512, 0, stream>>>(h2, w1b, 4 * Cc, Cc, 4 * Cc, h3, b1);
  // FFN2: split-K=2 (256 blocks); both splits -> bf16 partials
  gemm_ffn2_kernel<<<dim3(256), 512, 0, stream>>>(h3, w2b, Cc, 4 * Cc, p0b, p1b);
  // out += p0 + p1 + bias
  add_pp_kernel<<<dim3(2048), 256, 0, stream>>>(out, p0b, p1b, b2);
}

// Round 20
// 358.900 us; speedup vs baseline: 1.0418x; 1.0033x over previous
//
#include <hip/hip_runtime.h>
#include <stdint.h>

#define Bb 4
#define Tt 2048
#define Cc 1024
#define Hh 16
#define HSs 64

typedef __attribute__((ext_vector_type(8))) __bf16 bf16x8;
typedef __attribute__((ext_vector_type(4))) float f32x4;

// round-half-up bf16 cast: 2 VALU ops (vs 4 for RNE). Ties differ from RNE only.
__device__ __forceinline__ ushort f2bf(float f){
  union { float f; uint u; } c; c.f = f;
  return (ushort)((c.u + 0x8000u) >> 16);
}
__device__ __forceinline__ float bf2f(ushort u){
  union { uint u; float f; } c; c.u = ((uint)u) << 16; return c.f;
}

// async global->LDS, 16B per lane. LDS dest wave-uniform base; HW adds lane*16.
__device__ __forceinline__ void gload16(const void* g, void* l){
  __builtin_amdgcn_global_load_lds(
      (__attribute__((address_space(1))) void*)(g),
      (__attribute__((address_space(3))) void*)(l), 16, 0, 0);
}

// ---------------- prep: weight casts (blocks 0..11263) + LN1 (blocks 11264..19455) ----------------
// The two workloads are independent; merging packs two memory-bound phases
// into one dispatch (co-resident, ~max instead of sum) and saves a launch.
__global__ __launch_bounds__(256) void prep_kernel(
    const float* __restrict__ wq, const float* __restrict__ wk,
    const float* __restrict__ wv, const float* __restrict__ w1,
    const float* __restrict__ w2, ushort* __restrict__ wout,
    const float* __restrict__ x,
    const float* __restrict__ gw, const float* __restrict__ bw,
    ushort* __restrict__ hout){
  int bid = blockIdx.x, tid = threadIdx.x;
  if (bid < 11264){
    int i = (bid * 256 + tid) * 4;
    const float* src; int off;
    if      (i <  1048576){ src = wq; off = i; }
    else if (i <  2097152){ src = wk; off = i - 1048576; }
    else if (i <  3145728){ src = wv; off = i - 2097152; }
    else if (i <  7340032){ src = w1; off = i - 3145728; }
    else                  { src = w2; off = i - 7340032; }
    float4 v = *(const float4*)(src + off);
    ushort4 o; o.x = f2bf(v.x); o.y = f2bf(v.y); o.z = f2bf(v.z); o.w = f2bf(v.w);
    *(ushort4*)(wout + i) = o;
    return;
  }
  int row = bid - 11264;
  size_t base = (size_t)row * Cc + tid * 4;
  float4 xv = *(const float4*)(x + base);
  float s  = xv.x + xv.y + xv.z + xv.w;
  float ss = xv.x*xv.x + xv.y*xv.y + xv.z*xv.z + xv.w*xv.w;
  #pragma unroll
  for (int off = 1; off < 64; off <<= 1){ s += __shfl_xor(s, off); ss += __shfl_xor(ss, off); }
  __shared__ float red[8];
  int wid = tid >> 6, lane = tid & 63;
  if (lane == 0){ red[wid] = s; red[4 + wid] = ss; }
  __syncthreads();
  s  = red[0] + red[1] + red[2] + red[3];
  ss = red[4] + red[5] + red[6] + red[7];
  float mu = s * (1.0f / Cc);
  float rstd = rsqrtf(ss * (1.0f / Cc) - mu * mu + 1e-5f);
  float4 gv = *(const float4*)(gw + tid * 4);
  float4 bv = *(const float4*)(bw + tid * 4);
  ushort4 o;
  o.x = f2bf((xv.x - mu) * rstd * gv.x + bv.x);
  o.y = f2bf((xv.y - mu) * rstd * gv.y + bv.y);
  o.z = f2bf((xv.z - mu) * rstd * gv.z + bv.z);
  o.w = f2bf((xv.w - mu) * rstd * gv.w + bv.w);
  *(ushort4*)(hout + base) = o;
}

// ---------------- FFN2 finish: out += p0 + p1 + bias ----------------
__global__ __launch_bounds__(256) void add_pp_kernel(float* __restrict__ out,
    const ushort* __restrict__ p0b, const ushort* __restrict__ p1b,
    const float* __restrict__ bias){
  for (int it = 0; it < 4; ++it){
    size_t i4 = (size_t)it * 2048 * 256 + blockIdx.x * 256 + threadIdx.x;
    size_t i = i4 * 4;
    float4 o = *(const float4*)(out + i);
    ushort4 a = *(const ushort4*)(p0b + i);
    ushort4 b = *(const ushort4*)(p1b + i);
    float4 bv = *(const float4*)(bias + ((i4 & 255) * 4));
    o.x += bf2f(a.x) + bf2f(b.x) + bv.x;
    o.y += bf2f(a.y) + bf2f(b.y) + bv.y;
    o.z += bf2f(a.z) + bf2f(b.z) + bv.z;
    o.w += bf2f(a.w) + bf2f(b.w) + bv.w;
    *(float4*)(out + i) = o;
  }
}

// ---------------- LN2: x2 = x + attn -> d_out, h2 = LN(x2) -> bf16 ----------------
__global__ __launch_bounds__(256) void ln2_kernel(const float* __restrict__ x,
    const ushort* __restrict__ attnb,
    const float* __restrict__ gw, const float* __restrict__ bw,
    float* __restrict__ x2, ushort* __restrict__ hout){
  int row = blockIdx.x, tid = threadIdx.x;
  size_t base = (size_t)row * Cc + tid * 4;
  float4 xv = *(const float4*)(x + base);
  ushort4 av = *(const ushort4*)(attnb + base);
  xv.x += bf2f(av.x); xv.y += bf2f(av.y); xv.z += bf2f(av.z); xv.w += bf2f(av.w);
  *(float4*)(x2 + base) = xv;
  float s  = xv.x + xv.y + xv.z + xv.w;
  float ss = xv.x*xv.x + xv.y*xv.y + xv.z*xv.z + xv.w*xv.w;
  #pragma unroll
  for (int off = 1; off < 64; off <<= 1){ s += __shfl_xor(s, off); ss += __shfl_xor(ss, off); }
  __shared__ float red[8];
  int wid = tid >> 6, lane = tid & 63;
  if (lane == 0){ red[wid] = s; red[4 + wid] = ss; }
  __syncthreads();
  s  = red[0] + red[1] + red[2] + red[3];
  ss = red[4] + red[5] + red[6] + red[7];
  float mu = s * (1.0f / Cc);
  float rstd = rsqrtf(ss * (1.0f / Cc) - mu * mu + 1e-5f);
  float4 gv = *(const float4*)(gw + tid * 4);
  float4 bv = *(const float4*)(bw + tid * 4);
  ushort4 o;
  o.x = f2bf((xv.x - mu) * rstd * gv.x + bv.x);
  o.y = f2bf((xv.y - mu) * rstd * gv.y + bv.y);
  o.z = f2bf((xv.z - mu) * rstd * gv.z + bv.z);
  o.w = f2bf((xv.w - mu) * rstd * gv.w + bv.w);
  *(ushort4*)(hout + base) = o;
}

// =====================================================================
// 256x256 GEMM (R13 pipelined structure, best measured):
// MODE 0: QKV scatter (q pre-scaled by 0.125*log2e). MODE 1: SiLU+bias bf16.
// MODE 3: split-K=2, both splits store bf16 partials.
// =====================================================================
#define MFMA_QUAD(AF, SI, QI, BQ) \
  { \
    _Pragma("unroll") \
    for (int mi = 0; mi < 4; ++mi){ \
      acc[(SI)*4+mi][(QI)*2+0] = __builtin_amdgcn_mfma_f32_16x16x32_bf16(AF[mi][0], BQ[0][0], acc[(SI)*4+mi][(QI)*2+0], 0,0,0); \
      acc[(SI)*4+mi][(QI)*2+0] = __builtin_amdgcn_mfma_f32_16x16x32_bf16(AF[mi][1], BQ[0][1], acc[(SI)*4+mi][(QI)*2+0], 0,0,0); \
      acc[(SI)*4+mi][(QI)*2+1] = __builtin_amdgcn_mfma_f32_16x16x32_bf16(AF[mi][0], BQ[1][0], acc[(SI)*4+mi][(QI)*2+1], 0,0,0); \
      acc[(SI)*4+mi][(QI)*2+1] = __builtin_amdgcn_mfma_f32_16x16x32_bf16(AF[mi][1], BQ[1][1], acc[(SI)*4+mi][(QI)*2+1], 0,0,0); \
    } \
  }

#define GEMM_TOP() { asm volatile("s_waitcnt lgkmcnt(0)" ::: "memory"); \
                     __builtin_amdgcn_sched_barrier(0); __builtin_amdgcn_s_setprio(1); }
#define GEMM_MID() { __builtin_amdgcn_s_setprio(0); }
#define GEMM_BAR() { __builtin_amdgcn_s_barrier(); }

template<int MODE>
__device__ __forceinline__ void gemm256_body(
    const ushort* __restrict__ A, const ushort* __restrict__ Bw,
    int N, int K, int ldO,
    ushort* __restrict__ obf, float* __restrict__ of32,
    ushort* __restrict__ p1b, const float* __restrict__ bias)
{
  __shared__ __align__(16) ushort lds[2][2][2][128 * 64];  // [buf][A/B][half][128r x 64k]
  int tid = threadIdx.x, lane = tid & 63, wid = tid >> 6;
  int wm = wid >> 2, wn = wid & 3;
  int c = lane & 15, g = lane >> 4;
  int brow0 = (wn & 1) * 64;

  int nwg = gridDim.x, bid = blockIdx.x;
  int wgid = (bid & 7) * (nwg >> 3) + (bid >> 3);
  int m0, n0, koff = 0;
  if (MODE == 3){
    int split = wgid >> 7, rem = wgid & 127;   // 2 x (32 m-tiles x 4 n-tiles)
    m0 = (rem >> 2) << 8; n0 = (rem & 3) << 8; koff = split << 11;
  } else {
    int nTn = N >> 8;
    m0 = (wgid / nTn) << 8; n0 = (wgid % nTn) << 8;
  }

  const ushort* Ag = A  + (size_t)m0 * K + koff;
  const ushort* Bg = Bw + (size_t)n0 * K + koff;

  auto stage = [&](const ushort* gbase, int t, int ab, int hb){
    #pragma unroll
    for (int j = 0; j < 2; ++j){
      int d = j * 8192 + wid * 1024 + lane * 16;
      int row = d >> 7;
      int colb = (d & 127) ^ ((row & 7) << 4);
      gload16((const char*)gbase + ((size_t)(hb * 128 + row) * K + t * 64) * 2 + colb,
              (char*)&lds[t & 1][ab][hb][0] + j * 8192 + wid * 1024);
    }
  };

  f32x4 acc[8][4] = {};
  bf16x8 af0[4][2], af1[4][2], bq0[2][2], bq1[2][2];

  auto readA = [&](const char* Ap, int sub, bf16x8 (&af)[4][2]){
    #pragma unroll
    for (int mi = 0; mi < 4; ++mi){
      int row = sub * 64 + mi * 16 + c, sw = (row & 7) << 4;
      af[mi][0] = *(const bf16x8*)(Ap + row * 128 + ((g * 16) ^ sw));
      af[mi][1] = *(const bf16x8*)(Ap + row * 128 + ((64 + g * 16) ^ sw));
    }
  };
  auto readB = [&](const char* Bp, int hb, bf16x8 (&bq)[2][2]){
    #pragma unroll
    for (int nj = 0; nj < 2; ++nj){
      int row = brow0 + hb * 32 + nj * 16 + c, sw = (row & 7) << 4;
      bq[nj][0] = *(const bf16x8*)(Bp + row * 128 + ((g * 16) ^ sw));
      bq[nj][1] = *(const bf16x8*)(Bp + row * 128 + ((64 + g * 16) ^ sw));
    }
  };

  int nt = (MODE == 3) ? (K >> 7) : (K >> 6);

  // ---- prologue ----
  stage(Ag, 0, 0, 0); stage(Ag, 0, 0, 1);
  stage(Bg, 0, 1, 0); stage(Bg, 0, 1, 1);
  if (nt > 1){
    stage(Bg, 1, 1, 0); stage(Bg, 1, 1, 1);
    stage(Ag, 1, 0, 0); stage(Ag, 1, 0, 1);
    asm volatile("s_waitcnt vmcnt(8)" ::: "memory");
  } else {
    asm volatile("s_waitcnt vmcnt(0)" ::: "memory");
  }
  __builtin_amdgcn_s_barrier();
  readA((const char*)&lds[0][0][wm][0], 0, af0);
  readB((const char*)&lds[0][1][wn >> 1][0], 0, bq0);

  for (int t = 0; t < nt; ++t){
    const char* Abuf  = (const char*)&lds[t & 1][0][wm][0];
    const char* Bbuf  = (const char*)&lds[t & 1][1][wn >> 1][0];
    const char* AbufN = (const char*)&lds[(t + 1) & 1][0][wm][0];
    const char* BbufN = (const char*)&lds[(t + 1) & 1][1][wn >> 1][0];

    GEMM_TOP();
    MFMA_QUAD(af0, 0, 0, bq0);
    GEMM_MID();
    readB(Bbuf, 1, bq1);
    GEMM_BAR();                                  // B1

    GEMM_TOP();
    MFMA_QUAD(af0, 0, 1, bq1);
    GEMM_MID();
    readA(Abuf, 1, af1);
    GEMM_BAR();                                  // B2

    GEMM_TOP();
    MFMA_QUAD(af1, 1, 0, bq0);
    GEMM_MID();
    if (t + 2 < nt){
      stage(Bg, t + 2, 1, 0);
      asm volatile("s_waitcnt vmcnt(2)" ::: "memory");
    } else {
      asm volatile("s_waitcnt vmcnt(0)" ::: "memory");
    }
    GEMM_BAR();                                  // B3 (tile t+1 landed)

    GEMM_TOP();
    MFMA_QUAD(af1, 1, 1, bq1);
    GEMM_MID();
    if (t + 1 < nt){
      readA(AbufN, 0, af0);
      readB(BbufN, 0, bq0);
    }
    if (t + 2 < nt){
      stage(Bg, t + 2, 1, 1);
      stage(Ag, t + 2, 0, 0);
      stage(Ag, t + 2, 0, 1);
    }
    GEMM_BAR();                                  // B4
  }

  #pragma unroll
  for (int mi = 0; mi < 8; ++mi){
    #pragma unroll
    for (int ni = 0; ni < 4; ++ni){
      #pragma unroll
      for (int r = 0; r < 4; ++r){
        float v = acc[mi][ni][r];
        int m = m0 + wm * 128 + mi * 16 + g * 4 + r;
        int n = n0 + wn * 64 + ni * 16 + c;
        if (MODE == 0){
          int which = n >> 10;
          int nn = n & 1023;
          int b = m >> 11, t = m & (Tt - 1);
          int h = nn >> 6, d = nn & 63;
          // q scale = 0.125 (softmax) * log2(e) (exp2 fold in attn)
          float vv = (which == 0) ? v * 0.18033688f : v;
          size_t base = (size_t)which * (size_t)(Bb * Tt * Cc);
          size_t idx = (which == 2)
              ? ((((size_t)(b * Hh + h)) * HSs + d) * Tt + t)     // V^T [B,H,HS,T]
              : ((((size_t)(b * Hh + h)) * Tt + t) * HSs + d);    // Q,K [B,H,T,HS]
          obf[base + idx] = f2bf(vv);
        } else if (MODE == 1){
          v += bias[n];
          float sv = v / (1.0f + __expf(-v));   // SiLU
          obf[(size_t)m * ldO + n] = f2bf(sv);
        } else {
          size_t idx = (size_t)m * N + n;
          if (koff == 0) obf[idx] = f2bf(v);    // split 0 partial (bf16)
          else           p1b[idx] = f2bf(v);    // split 1 partial (bf16)
        }
      }
    }
  }
}

__global__ __launch_bounds__(512, 2) void gemm_qkv_kernel(
    const ushort* __restrict__ A, const ushort* __restrict__ Bw, int N, int K,
    ushort* __restrict__ obf){
  gemm256_body<0>(A, Bw, N, K, 0, obf, nullptr, nullptr, nullptr);
}
__global__ __launch_bounds__(512, 2) void gemm_ffn1_kernel(
    const ushort* __restrict__ A, const ushort* __restrict__ Bw, int N, int K, int ldO,
    ushort* __restrict__ obf, const float* __restrict__ bias){
  gemm256_body<1>(A, Bw, N, K, ldO, obf, nullptr, nullptr, bias);
}
__global__ __launch_bounds__(512, 2) void gemm_ffn2_kernel(
    const ushort* __restrict__ A, const ushort* __restrict__ Bw, int N, int K,
    ushort* __restrict__ p0b, ushort* __restrict__ p1b){
  gemm256_body<3>(A, Bw, N, K, N, p0b, nullptr, p1b, nullptr);
}

// ---------------- causal flash attention (ring-4, pair-chunk, vmcnt(8);
// no-shift softmax with exp2 folded into q pre-scale; setprio on MFMA) ----------------
__global__ __launch_bounds__(256, 2) void attn_kernel(
    const ushort* __restrict__ q, const ushort* __restrict__ k,
    const ushort* __restrict__ vt, ushort* __restrict__ attnb)
{
  __shared__ __align__(16) ushort Ksm[4][64 * 64];
  __shared__ __align__(16) ushort Vsm[4][64 * 64];
  __shared__ __align__(16) ushort Pl[4][32 * 64];

  int bh  = blockIdx.y;
  int p   = blockIdx.x;                       // 0..7
  int tid = threadIdx.x, wid = tid >> 6, lane = tid & 63;
  int g = lane >> 4, c = lane & 15;
  int qbA = 15 - p, qbB = p;                  // A = long tile, B = short tile
  int q0A = qbA * 128 + wid * 32;
  int q0B = qbB * 128 + wid * 32;
  const ushort* Qb = q  + (size_t)bh * Tt * HSs;
  const ushort* Kb = k  + (size_t)bh * Tt * HSs;
  const ushort* Vt = vt + (size_t)bh * HSs * Tt;
  char* Pw = (char*)&Pl[wid][0];

  auto stageKV = [&](int bsel, int s0){
    #pragma unroll
    for (int hb = 0; hb < 2; ++hb){
      int i = wid + hb * 4;                   // 0..7
      int row = i * 8 + (lane >> 3);          // 0..63
      int col = ((lane & 7) ^ (row & 7)) * 8; // inverse-swizzled source
      gload16(Kb + (size_t)(s0 + row) * HSs + col, &Ksm[bsel][i * 512]);
      gload16(Vt + (size_t)row * Tt + s0 + col,    &Vsm[bsel][i * 512]);
    }
  };

  bf16x8 qfA[2][2], qfB[2][2];
  #pragma unroll
  for (int mi = 0; mi < 2; ++mi)
    #pragma unroll
    for (int ks = 0; ks < 2; ++ks){
      qfA[mi][ks] = *(const bf16x8*)(Qb + (size_t)(q0A + mi * 16 + c) * HSs + ks * 32 + g * 8);
      qfB[mi][ks] = *(const bf16x8*)(Qb + (size_t)(q0B + mi * 16 + c) * HSs + ks * 32 + g * 8);
    }

  f32x4 oA[2][4] = {}, oB[2][4] = {};
  float lA[2][4] = {}, lB[2][4] = {};

  auto computeTile = [&](bf16x8 (&qf)[2][2], f32x4 (&o)[2][4],
                         float (&lpart)[2][4],
                         int q0w, int s0, const char* Kbuf, const char* Vbuf){
    f32x4 S[2][4] = {};
    bf16x8 kf[4][2];
    #pragma unroll
    for (int ni = 0; ni < 4; ++ni)
      #pragma unroll
      for (int ks = 0; ks < 2; ++ks)
        kf[ni][ks] = *(const bf16x8*)(Kbuf + (ni * 16 + c) * 128 + (((ks * 4 + g) ^ (c & 7)) << 4));
    __builtin_amdgcn_s_setprio(1);
    #pragma unroll
    for (int mi = 0; mi < 2; ++mi)
      #pragma unroll
      for (int ni = 0; ni < 4; ++ni)
        #pragma unroll
        for (int ks = 0; ks < 2; ++ks)
          S[mi][ni] = __builtin_amdgcn_mfma_f32_16x16x32_bf16(qf[mi][ks], kf[ni][ks], S[mi][ni], 0, 0, 0);
    __builtin_amdgcn_s_setprio(0);

    if (s0 + 63 > q0w){   // diagonal chunk: causal mask
      #pragma unroll
      for (int mi = 0; mi < 2; ++mi)
        #pragma unroll
        for (int ni = 0; ni < 4; ++ni)
          #pragma unroll
          for (int r = 0; r < 4; ++r){
            int tl = q0w + mi * 16 + g * 4 + r, sl = s0 + ni * 16 + c;
            if (sl > tl) S[mi][ni][r] = -1e30f;
          }
    }

    // S already includes log2(e) via q pre-scale: p = exp2(S). Masked -> 0.
    #pragma unroll
    for (int mi = 0; mi < 2; ++mi)
      #pragma unroll
      for (int r = 0; r < 4; ++r){
        int row = mi * 16 + g * 4 + r;
        float pp[4];
        #pragma unroll
        for (int ni = 0; ni < 4; ++ni){
          pp[ni] = exp2f(S[mi][ni][r]);
          *(ushort*)(Pw + row * 128 + (((ni * 32 + 2 * c) ^ ((row & 7) << 4)))) = f2bf(pp[ni]);
        }
        lpart[mi][r] += (pp[0] + pp[1]) + (pp[2] + pp[3]);
      }

    bf16x8 vf[4][2];
    #pragma unroll
    for (int dt = 0; dt < 4; ++dt)
      #pragma unroll
      for (int ks = 0; ks < 2; ++ks)
        vf[dt][ks] = *(const bf16x8*)(Vbuf + (dt * 16 + c) * 128 + (((ks * 4 + g) ^ (c & 7)) << 4));
    __builtin_amdgcn_s_setprio(1);
    #pragma unroll
    for (int mi = 0; mi < 2; ++mi){
      #pragma unroll
      for (int ks = 0; ks < 2; ++ks){
        bf16x8 pf = *(const bf16x8*)(Pw + (mi * 16 + c) * 128 + ((((ks * 4 + g) ^ (c & 7)) << 4)));
        #pragma unroll
        for (int dt = 0; dt < 4; ++dt)
          o[mi][dt] = __builtin_amdgcn_mfma_f32_16x16x32_bf16(pf, vf[dt][ks], o[mi][dt], 0, 0, 0);
      }
    }
    __builtin_amdgcn_s_setprio(0);
  };

  int nchA = 2 * qbA + 2;                     // even, >= 18

  stageKV(0, 0);
  stageKV(1, 64);

  for (int ch = 0; ch < nchA; ch += 2){
    bool staged = (ch + 2 < nchA);
    if (staged){
      stageKV((ch + 2) & 3, (ch + 2) * 64);
      stageKV((ch + 3) & 3, (ch + 3) * 64);
      asm volatile("s_waitcnt vmcnt(8)" ::: "memory");   // (ch,ch+1) landed
    } else {
      asm volatile("s_waitcnt vmcnt(0)" ::: "memory");
    }
    __builtin_amdgcn_sched_barrier(0);
    __builtin_amdgcn_s_barrier();

    {
      int s0 = ch * 64;
      const char* Kbuf = (const char*)&Ksm[ch & 3][0];
      const char* Vbuf = (const char*)&Vsm[ch & 3][0];
      if (s0 <= q0A + 31) computeTile(qfA, oA, lA, q0A, s0, Kbuf, Vbuf);
      if (s0 <= q0B + 31) computeTile(qfB, oB, lB, q0B, s0, Kbuf, Vbuf);
    }
    {
      int s0 = (ch + 1) * 64;
      const char* Kbuf = (const char*)&Ksm[(ch + 1) & 3][0];
      const char* Vbuf = (const char*)&Vsm[(ch + 1) & 3][0];
      if (s0 <= q0A + 31) computeTile(qfA, oA, lA, q0A, s0, Kbuf, Vbuf);
      if (s0 <= q0B + 31) computeTile(qfB, oB, lB, q0B, s0, Kbuf, Vbuf);
    }

    __builtin_amdgcn_sched_barrier(0);
    __builtin_amdgcn_s_barrier();             // reads done before next-iter stages
  }

  int b = bh >> 4, h = bh & 15;
  #pragma unroll
  for (int mi = 0; mi < 2; ++mi)
    #pragma unroll
    for (int r = 0; r < 4; ++r){
      float la = lA[mi][r];
      la += __shfl_xor(la, 1); la += __shfl_xor(la, 2);
      la += __shfl_xor(la, 4); la += __shfl_xor(la, 8);
      float lia = 1.0f / la;
      float lb = lB[mi][r];
      lb += __shfl_xor(lb, 1); lb += __shfl_xor(lb, 2);
      lb += __shfl_xor(lb, 4); lb += __shfl_xor(lb, 8);
      float lib = 1.0f / lb;
      #pragma unroll
      for (int dt = 0; dt < 4; ++dt){
        int tA = q0A + mi * 16 + g * 4 + r;
        int tB = q0B + mi * 16 + g * 4 + r;
        attnb[((size_t)(b * Tt + tA)) * Cc + h * HSs + dt * 16 + c] = f2bf(oA[mi][dt][r] * lia);
        attnb[((size_t)(b * Tt + tB)) * Cc + h * HSs + dt * 16 + c] = f2bf(oB[mi][dt][r] * lib);
      }
    }
}

extern "C" void kernel_launch(void* const* d_in, const int* in_sizes, int n_in,
                              void* d_out, int out_size, void* d_ws, size_t ws_size,
                              hipStream_t stream) {
  (void)in_sizes; (void)n_in; (void)out_size; (void)ws_size;
  const float* x    = (const float*)d_in[0];
  const float* wq   = (const float*)d_in[2];
  const float* wk   = (const float*)d_in[3];
  const float* wv   = (const float*)d_in[4];
  const float* ln1g = (const float*)d_in[5];
  const float* ln1b = (const float*)d_in[6];
  const float* ln2g = (const float*)d_in[7];
  const float* ln2b = (const float*)d_in[8];
  const float* w1   = (const float*)d_in[9];
  const float* b1   = (const float*)d_in[10];
  const float* w2   = (const float*)d_in[11];
  const float* b2   = (const float*)d_in[12];
  float* out = (float*)d_out;

  char* ws = (char*)d_ws;
  const size_t SZ_ACT = (size_t)Bb * Tt * Cc * 2;
  ushort* h1    = (ushort*)(ws);
  ushort* qbuf  = (ushort*)(ws + SZ_ACT);
  ushort* kbuf  = (ushort*)(ws + 2 * SZ_ACT);
  ushort* vbuf  = (ushort*)(ws + 3 * SZ_ACT);   // V^T [B,H,HS,T]
  ushort* attnb = (ushort*)(ws + 4 * SZ_ACT);
  ushort* h2    = (ushort*)(ws + 5 * SZ_ACT);
  ushort* h3    = (ushort*)(ws + 6 * SZ_ACT);
  ushort* p0b   = (ushort*)(ws + SZ_ACT);       // bf16 partials in dead q/k bufs
  ushort* p1b   = (ushort*)(ws + 2 * SZ_ACT);
  char*   wsw   = ws + 6 * SZ_ACT + (size_t)Bb * Tt * 4 * Cc * 2;
  ushort* wqb = (ushort*)(wsw);                 // wq,wk,wv,w1,w2 contiguous bf16
  ushort* w1b = (ushort*)(wsw + 3 * (size_t)Cc * Cc * 2);
  ushort* w2b = (ushort*)(wsw + 3 * (size_t)Cc * Cc * 2 + (size_t)4 * Cc * Cc * 2);

  // merged weight-cast + LN1 (independent workloads packed into one dispatch)
  prep_kernel<<<dim3(11264 + Bb * Tt), 256, 0, stream>>>(
      wq, wk, wv, w1, w2, wqb, x, ln1g, ln1b, h1);

  // fused QKV projection: [8192,3072] = h1 @ [3072,1024]^T
  gemm_qkv_kernel<<<dim3(32 * 12), 512, 0, stream>>>(h1, wqb, 3 * Cc, Cc, qbuf);

  attn_kernel<<<dim3(8, Bb * Hh), 256, 0, stream>>>(qbuf, kbuf, vbuf, attnb);

  ln2_kernel<<<dim3(Bb * Tt), 256, 0, stream>>>(x, attnb, ln2g, ln2b, out, h2);

  // FFN1: single dispatch, [8192,4096] = h2 @ w1^T (512 blocks = 2 rounds)
  gemm_ffn1_kernel<<<dim3(32 * 16), 512, 0, stream>>>(h2, w1b, 4 * Cc, Cc, 4 * Cc, h3, b1);
  // FFN2: split-K=2 (256 blocks); both splits -> bf16 partials
  gemm_ffn2_kernel<<<dim3(256), 512, 0, stream>>>(h3, w2b, Cc, 4 * Cc, p0b, p1b);
  // out += p0 + p1 + bias
  add_pp_kernel<<<dim3(2048), 256, 0, stream>>>(out, p0b, p1b, b2);
}